// Round 6
// baseline (439.606 us; speedup 1.0000x reference)
//
#include <hip/hip_runtime.h>

#define DD 160
#define HH 160
#define WW 160
#define PL (HH*WW)       // one z-plane = 25600 voxels
#define S (DD*PL)        // 4,096,000 voxels

__device__ __forceinline__ float fmul(float a, float b){ return __fmul_rn(a,b); }
__device__ __forceinline__ float fadd(float a, float b){ return __fadd_rn(a,b); }
__device__ __forceinline__ float fsub(float a, float b){ return __fsub_rn(a,b); }

// ---------------------------------------------------------------------------
// float4-padded path (one dwordx4 per tap). A = d_ws, B = out[0:4S).
// ---------------------------------------------------------------------------

// ddf0 = (dvf0*(1-w) + dvf1*w) / 32, planar in -> float4-interleaved out
__global__ __launch_bounds__(256) void init4_kernel(const float* __restrict__ dvf0,
                                                    const float* __restrict__ dvf1,
                                                    const float* __restrict__ wp,
                                                    float4* __restrict__ outi) {
    int p = (blockIdx.x * 256 + threadIdx.x) * 4;   // 4000 blocks cover S exactly
    float w = wp[0];
    float onew = fsub(1.0f, w);
    float a0[4], a1[4], a2[4], b0[4], b1[4], b2[4];
    *(float4*)a0 = *(const float4*)(dvf0 + p);
    *(float4*)a1 = *(const float4*)(dvf0 + S + p);
    *(float4*)a2 = *(const float4*)(dvf0 + 2 * S + p);
    *(float4*)b0 = *(const float4*)(dvf1 + p);
    *(float4*)b1 = *(const float4*)(dvf1 + S + p);
    *(float4*)b2 = *(const float4*)(dvf1 + 2 * S + p);
    #pragma unroll
    for (int j = 0; j < 4; ++j) {
        float o0 = fmul(fadd(fmul(a0[j], onew), fmul(b0[j], w)), 0.03125f);
        float o1 = fmul(fadd(fmul(a1[j], onew), fmul(b1[j], w)), 0.03125f);
        float o2 = fmul(fadd(fmul(a2[j], onew), fmul(b2[j], w)), 0.03125f);
        outi[p + j] = make_float4(o0, o1, o2, 0.0f);
    }
}

// out = in + trilinear_warp(in, in). float4 taps; 32x2 wave footprint;
// 2 voxels/thread (z). Grid 8000; swizzle -> 20-plane slab per XCD.
template<bool PLANAR>
__global__ __launch_bounds__(256) void warp_step4(const float4* __restrict__ in,
                                                  float4* __restrict__ out4,
                                                  float* __restrict__ outp) {
    int b  = (blockIdx.x & 7) * 1000 + (blockIdx.x >> 3);
    int ix = b % 5;
    int r  = b / 5;
    int iy = r % 20;
    int iz = r / 20;                 // 0..79
    int lane = threadIdx.x & 63, wid = threadIdx.x >> 6;
    int x  = (ix << 5) | (lane & 31);
    int y  = (iy << 3) | (wid << 1) | (lane >> 5);
    int z0 = iz << 1;
    int p0 = (z0 * HH + y) * WW + x;

    float4 ctr[2];
    ctr[0] = in[p0];
    ctr[1] = in[p0 + PL];

    #pragma unroll
    for (int j = 0; j < 2; ++j) {
        int z = z0 + j;
        int p = p0 + j * PL;
        float vd = ctr[j].x, vh = ctr[j].y, vw = ctr[j].z;
        float cd = fadd((float)z, vd);
        float ch = fadd((float)y, vh);
        float cw = fadd((float)x, vw);

        float d0 = floorf(cd), h0 = floorf(ch), w0 = floorf(cw);
        float fd = fsub(cd, d0), fh = fsub(ch, h0), fw = fsub(cw, w0);
        float gd = fsub(1.0f, fd), gh = fsub(1.0f, fh), gw = fsub(1.0f, fw);
        int d0i = (int)d0, h0i = (int)h0, w0i = (int)w0;

        int   qa[8];
        float wt[8];
        #pragma unroll
        for (int t = 0; t < 8; ++t) {
            int dd = t >> 2, dh = (t >> 1) & 1, dw = t & 1;
            int di = d0i + dd, hi = h0i + dh, wi = w0i + dw;
            bool valid = (di >= 0) & (di < DD) & (hi >= 0) & (hi < HH)
                       & (wi >= 0) & (wi < WW);
            float wgt = fmul(fmul(dd ? fd : gd, dh ? fh : gh), dw ? fw : gw);
            wt[t] = valid ? wgt : 0.0f;     // 0*v == ref's v*0 (values finite)
            int dc = min(max(di, 0), DD - 1);
            int hc = min(max(hi, 0), HH - 1);
            int wc = min(max(wi, 0), WW - 1);
            qa[t] = (dc * HH + hc) * WW + wc;
        }
        float4 g[8];
        #pragma unroll
        for (int t = 0; t < 8; ++t) g[t] = in[qa[t]];   // one dwordx4 per tap

        float acc0 = 0.0f, acc1 = 0.0f, acc2 = 0.0f;
        #pragma unroll
        for (int t = 0; t < 8; ++t) {
            acc0 = fadd(acc0, fmul(g[t].x, wt[t]));
            acc1 = fadd(acc1, fmul(g[t].y, wt[t]));
            acc2 = fadd(acc2, fmul(g[t].z, wt[t]));
        }
        float r0 = fadd(vd, acc0);
        float r1 = fadd(vh, acc1);
        float r2 = fadd(vw, acc2);

        if (PLANAR) {
            outp[p] = r0; outp[S + p] = r1; outp[2 * S + p] = r2;
        } else {
            out4[p] = make_float4(r0, r1, r2, 0.0f);
        }
    }
}

// dense pack: [img, cav(float), cor(float), 0] per voxel
__global__ __launch_bounds__(256) void pack_kernel(const float* __restrict__ img,
                                                   const int* __restrict__ cav,
                                                   const int* __restrict__ cor,
                                                   float4* __restrict__ out) {
    int p = (blockIdx.x * 256 + threadIdx.x) * 4;   // 4000 blocks
    float im[4]; int cv[4]; int co[4];
    *(float4*)im = *(const float4*)(img + p);
    *(int4*)cv   = *(const int4*)(cav + p);
    *(int4*)co   = *(const int4*)(cor + p);
    #pragma unroll
    for (int j = 0; j < 4; ++j)
        out[p + j] = make_float4(im[j], (float)cv[j], (float)co[j], 0.0f);
}

// img trilinear + labels via shared corner taps. ddf planar; packed float4 taps.
// Nearest-label corner rintf(c) is always floor(c) or floor(c)+1 -> one of the
// 8 trilinear corners; select with a cndmask tree, recompute validity exactly.
__global__ __launch_bounds__(256) void final4_kernel(const float* __restrict__ ddf,
                                                     const float4* __restrict__ packed,
                                                     float* __restrict__ out) {
    int b  = (blockIdx.x & 7) * 1000 + (blockIdx.x >> 3);
    int ix = b % 5;
    int r  = b / 5;
    int iy = r % 20;
    int iz = r / 20;                 // 0..79
    int lane = threadIdx.x & 63, wid = threadIdx.x >> 6;
    int x  = (ix << 5) | (lane & 31);
    int y  = (iy << 3) | (wid << 1) | (lane >> 5);
    int z0 = iz << 1;
    int p0 = (z0 * HH + y) * WW + x;

    float dzs[2], dhs[2], dws[2];
    #pragma unroll
    for (int j = 0; j < 2; ++j) {
        dzs[j] = ddf[p0 + j * PL];
        dhs[j] = ddf[S + p0 + j * PL];
        dws[j] = ddf[2 * S + p0 + j * PL];
    }

    #pragma unroll
    for (int j = 0; j < 2; ++j) {
        int z = z0 + j;
        int p = p0 + j * PL;
        float cd = fadd((float)z, dzs[j]);
        float ch = fadd((float)y, dhs[j]);
        float cw = fadd((float)x, dws[j]);

        float d0 = floorf(cd), h0 = floorf(ch), w0 = floorf(cw);
        float fd = fsub(cd, d0), fh = fsub(ch, h0), fw = fsub(cw, w0);
        float gd = fsub(1.0f, fd), gh = fsub(1.0f, fh), gw = fsub(1.0f, fw);
        int d0i = (int)d0, h0i = (int)h0, w0i = (int)w0;

        int   qa[8];
        float wt[8];
        #pragma unroll
        for (int t = 0; t < 8; ++t) {
            int dd = t >> 2, dh = (t >> 1) & 1, dw = t & 1;
            int di = d0i + dd, hi = h0i + dh, wi = w0i + dw;
            bool valid = (di >= 0) & (di < DD) & (hi >= 0) & (hi < HH)
                       & (wi >= 0) & (wi < WW);
            float wgt = fmul(fmul(dd ? fd : gd, dh ? fh : gh), dw ? fw : gw);
            wt[t] = valid ? wgt : 0.0f;
            int dc = min(max(di, 0), DD - 1);
            int hc = min(max(hi, 0), HH - 1);
            int wc = min(max(wi, 0), WW - 1);
            qa[t] = (dc * HH + hc) * WW + wc;
        }
        float4 g[8];
        #pragma unroll
        for (int t = 0; t < 8; ++t) g[t] = packed[qa[t]];

        float acc = 0.0f;
        #pragma unroll
        for (int t = 0; t < 8; ++t) acc = fadd(acc, fmul(g[t].x, wt[t]));
        out[p] = acc;

        // nearest labels: corner shared with trilinear taps
        int rd = (int)rintf(cd), rh = (int)rintf(ch), rw = (int)rintf(cw);
        bool vn = (rd >= 0) & (rd < DD) & (rh >= 0) & (rh < HH)
                & (rw >= 0) & (rw < WW);
        bool b2 = (rd != d0i), b1 = (rh != h0i), b0 = (rw != w0i);
        float cavv = b2 ? (b1 ? (b0 ? g[7].y : g[6].y) : (b0 ? g[5].y : g[4].y))
                        : (b1 ? (b0 ? g[3].y : g[2].y) : (b0 ? g[1].y : g[0].y));
        float corv = b2 ? (b1 ? (b0 ? g[7].z : g[6].z) : (b0 ? g[5].z : g[4].z))
                        : (b1 ? (b0 ? g[3].z : g[2].z) : (b0 ? g[1].z : g[0].z));
        out[S + p]     = vn ? cavv : 0.0f;
        out[2 * S + p] = vn ? corv : 0.0f;
    }
}

// ---------------------------------------------------------------------------
// Fallback path (R5): 12B interleave inside d_out only, no ws requirement.
// ---------------------------------------------------------------------------

__global__ __launch_bounds__(256) void init_kernel(const float* __restrict__ dvf0,
                                                   const float* __restrict__ dvf1,
                                                   const float* __restrict__ wp,
                                                   float* __restrict__ outi) {
    int p = (blockIdx.x * 256 + threadIdx.x) * 4;
    float w = wp[0];
    float onew = fsub(1.0f, w);
    float a0[4], a1[4], a2[4], b0[4], b1[4], b2[4];
    *(float4*)a0 = *(const float4*)(dvf0 + p);
    *(float4*)a1 = *(const float4*)(dvf0 + S + p);
    *(float4*)a2 = *(const float4*)(dvf0 + 2 * S + p);
    *(float4*)b0 = *(const float4*)(dvf1 + p);
    *(float4*)b1 = *(const float4*)(dvf1 + S + p);
    *(float4*)b2 = *(const float4*)(dvf1 + 2 * S + p);
    float o[12];
    #pragma unroll
    for (int j = 0; j < 4; ++j) {
        o[3*j]   = fmul(fadd(fmul(a0[j], onew), fmul(b0[j], w)), 0.03125f);
        o[3*j+1] = fmul(fadd(fmul(a1[j], onew), fmul(b1[j], w)), 0.03125f);
        o[3*j+2] = fmul(fadd(fmul(a2[j], onew), fmul(b2[j], w)), 0.03125f);
    }
    float* dst = outi + (size_t)3 * p;
    *(float4*)(dst)     = *(float4*)(o);
    *(float4*)(dst + 4) = *(float4*)(o + 4);
    *(float4*)(dst + 8) = *(float4*)(o + 8);
}

template<bool PLANAR>
__global__ __launch_bounds__(256) void warp_step(const float* __restrict__ in,
                                                 float* __restrict__ out) {
    int b  = (blockIdx.x & 7) * 1000 + (blockIdx.x >> 3);
    int ix = b % 5;
    int r  = b / 5;
    int iy = r % 20;
    int iz = r / 20;
    int lane = threadIdx.x & 63, wid = threadIdx.x >> 6;
    int x  = (ix << 5) | (lane & 31);
    int y  = (iy << 3) | (wid << 1) | (lane >> 5);
    int z0 = iz << 1;
    int p0 = (z0 * HH + y) * WW + x;

    float ctr[2][3];
    #pragma unroll
    for (int j = 0; j < 2; ++j) {
        const float* src = in + (size_t)3 * (p0 + j * PL);
        ctr[j][0] = src[0]; ctr[j][1] = src[1]; ctr[j][2] = src[2];
    }

    #pragma unroll
    for (int j = 0; j < 2; ++j) {
        int z = z0 + j;
        int p = p0 + j * PL;
        float vd = ctr[j][0], vh = ctr[j][1], vw = ctr[j][2];
        float cd = fadd((float)z, vd);
        float ch = fadd((float)y, vh);
        float cw = fadd((float)x, vw);

        float d0 = floorf(cd), h0 = floorf(ch), w0 = floorf(cw);
        float fd = fsub(cd, d0), fh = fsub(ch, h0), fw = fsub(cw, w0);
        float gd = fsub(1.0f, fd), gh = fsub(1.0f, fh), gw = fsub(1.0f, fw);
        int d0i = (int)d0, h0i = (int)h0, w0i = (int)w0;

        int   qa[8];
        float wt[8];
        #pragma unroll
        for (int t = 0; t < 8; ++t) {
            int dd = t >> 2, dh = (t >> 1) & 1, dw = t & 1;
            int di = d0i + dd, hi = h0i + dh, wi = w0i + dw;
            bool valid = (di >= 0) & (di < DD) & (hi >= 0) & (hi < HH)
                       & (wi >= 0) & (wi < WW);
            float wgt = fmul(fmul(dd ? fd : gd, dh ? fh : gh), dw ? fw : gw);
            wt[t] = valid ? wgt : 0.0f;
            int dc = min(max(di, 0), DD - 1);
            int hc = min(max(hi, 0), HH - 1);
            int wc = min(max(wi, 0), WW - 1);
            qa[t] = 3 * ((dc * HH + hc) * WW + wc);
        }
        float g[8][3];
        #pragma unroll
        for (int t = 0; t < 8; ++t) {
            g[t][0] = in[qa[t]];
            g[t][1] = in[qa[t] + 1];
            g[t][2] = in[qa[t] + 2];
        }
        float acc0 = 0.0f, acc1 = 0.0f, acc2 = 0.0f;
        #pragma unroll
        for (int t = 0; t < 8; ++t) {
            acc0 = fadd(acc0, fmul(g[t][0], wt[t]));
            acc1 = fadd(acc1, fmul(g[t][1], wt[t]));
            acc2 = fadd(acc2, fmul(g[t][2], wt[t]));
        }
        float r0 = fadd(vd, acc0);
        float r1 = fadd(vh, acc1);
        float r2 = fadd(vw, acc2);

        if (PLANAR) {
            out[p] = r0; out[S + p] = r1; out[2 * S + p] = r2;
        } else {
            float* dst = out + (size_t)3 * p;
            dst[0] = r0; dst[1] = r1; dst[2] = r2;
        }
    }
}

__global__ __launch_bounds__(256) void final_kernel(const float* __restrict__ ddf,
                                                    const float* __restrict__ image,
                                                    const int* __restrict__ cav,
                                                    const int* __restrict__ cor,
                                                    float* __restrict__ out) {
    int b  = (blockIdx.x & 7) * 1000 + (blockIdx.x >> 3);
    int ix = b % 5;
    int r  = b / 5;
    int iy = r % 20;
    int iz = r / 20;
    int lane = threadIdx.x & 63, wid = threadIdx.x >> 6;
    int x  = (ix << 5) | (lane & 31);
    int y  = (iy << 3) | (wid << 1) | (lane >> 5);
    int z0 = iz << 1;
    int p0 = (z0 * HH + y) * WW + x;

    float dzs[2], dhs[2], dws[2];
    #pragma unroll
    for (int j = 0; j < 2; ++j) {
        dzs[j] = ddf[p0 + j * PL];
        dhs[j] = ddf[S + p0 + j * PL];
        dws[j] = ddf[2 * S + p0 + j * PL];
    }

    #pragma unroll
    for (int j = 0; j < 2; ++j) {
        int z = z0 + j;
        int p = p0 + j * PL;
        float cd = fadd((float)z, dzs[j]);
        float ch = fadd((float)y, dhs[j]);
        float cw = fadd((float)x, dws[j]);

        float d0 = floorf(cd), h0 = floorf(ch), w0 = floorf(cw);
        float fd = fsub(cd, d0), fh = fsub(ch, h0), fw = fsub(cw, w0);
        float gd = fsub(1.0f, fd), gh = fsub(1.0f, fh), gw = fsub(1.0f, fw);
        int d0i = (int)d0, h0i = (int)h0, w0i = (int)w0;

        int   qa[8];
        float wt[8];
        #pragma unroll
        for (int t = 0; t < 8; ++t) {
            int dd = t >> 2, dh = (t >> 1) & 1, dw = t & 1;
            int di = d0i + dd, hi = h0i + dh, wi = w0i + dw;
            bool valid = (di >= 0) & (di < DD) & (hi >= 0) & (hi < HH)
                       & (wi >= 0) & (wi < WW);
            float wgt = fmul(fmul(dd ? fd : gd, dh ? fh : gh), dw ? fw : gw);
            wt[t] = valid ? wgt : 0.0f;
            int dc = min(max(di, 0), DD - 1);
            int hc = min(max(hi, 0), HH - 1);
            int wc = min(max(wi, 0), WW - 1);
            qa[t] = (dc * HH + hc) * WW + wc;
        }
        float g[8];
        #pragma unroll
        for (int t = 0; t < 8; ++t) g[t] = image[qa[t]];
        float acc = 0.0f;
        #pragma unroll
        for (int t = 0; t < 8; ++t) acc = fadd(acc, fmul(g[t], wt[t]));
        out[p] = acc;

        int di = (int)rintf(cd), hi = (int)rintf(ch), wi = (int)rintf(cw);
        bool valid = (di >= 0) & (di < DD) & (hi >= 0) & (hi < HH)
                   & (wi >= 0) & (wi < WW);
        int dc = min(max(di, 0), DD - 1);
        int hc = min(max(hi, 0), HH - 1);
        int wc = min(max(wi, 0), WW - 1);
        int q = (dc * HH + hc) * WW + wc;
        out[S + p]     = valid ? (float)cav[q] : 0.0f;
        out[2 * S + p] = valid ? (float)cor[q] : 0.0f;
    }
}

extern "C" void kernel_launch(void* const* d_in, const int* in_sizes, int n_in,
                              void* d_out, int out_size, void* d_ws, size_t ws_size,
                              hipStream_t stream) {
    const float* dvf0   = (const float*)d_in[0];
    const float* dvf1   = (const float*)d_in[1];
    const float* image  = (const float*)d_in[2];
    const int*   cav    = (const int*)d_in[3];
    const int*   cor    = (const int*)d_in[4];
    const float* w      = (const float*)d_in[5];

    float* out = (float*)d_out;

    const size_t need = (size_t)4 * S * sizeof(float);   // 65,536,000 B
    if (ws_size >= need) {
        float4* A = (float4*)d_ws;            // ping-pong buffer A (4S floats)
        float4* B = (float4*)d_out;           // ping-pong buffer B in out[0:4S)
        float*  ddf_planar = out + (size_t)3 * S;   // final ddf target

        init4_kernel<<<4000, 256, 0, stream>>>(dvf0, dvf1, w, A);
        warp_step4<false><<<8000, 256, 0, stream>>>(A, B, nullptr);   // s1
        warp_step4<false><<<8000, 256, 0, stream>>>(B, A, nullptr);   // s2
        warp_step4<false><<<8000, 256, 0, stream>>>(A, B, nullptr);   // s3
        warp_step4<false><<<8000, 256, 0, stream>>>(B, A, nullptr);   // s4
        warp_step4<true ><<<8000, 256, 0, stream>>>(A, nullptr, ddf_planar); // s5
        pack_kernel<<<4000, 256, 0, stream>>>(image, cav, cor, A);    // A free after s5
        final4_kernel<<<8000, 256, 0, stream>>>(ddf_planar, A, out);
    } else {
        // R5 fallback: 12B interleave, both halves of d_out
        float* bufA = out;
        float* bufB = out + (size_t)3 * S;
        init_kernel<<<4000, 256, 0, stream>>>(dvf0, dvf1, w, bufA);
        warp_step<false><<<8000, 256, 0, stream>>>(bufA, bufB);
        warp_step<false><<<8000, 256, 0, stream>>>(bufB, bufA);
        warp_step<false><<<8000, 256, 0, stream>>>(bufA, bufB);
        warp_step<false><<<8000, 256, 0, stream>>>(bufB, bufA);
        warp_step<true ><<<8000, 256, 0, stream>>>(bufA, bufB);
        final_kernel<<<8000, 256, 0, stream>>>(bufB, image, cav, cor, bufA);
    }
}